// Round 5
// baseline (1968.332 us; speedup 1.0000x reference)
//
#include <hip/hip_runtime.h>
#include <math.h>

#define N_NODES 8192
#define N_EDGES 32768
#define HID 8
#define FEAT 11          // HID + 3
#define E4   (N_EDGES/4) // 8192 float4 per matrix row (2^13)

// Native clang vector type. Incidence values are bitwise 0 or 1.0f, so an
// integer nonzero test is an exact float!=0 test (3 v_or + 1 v_cmp per 16B).
typedef int vint4 __attribute__((ext_vector_type(4)));

// ---------------------------------------------------------------------------
// Fused scan of BOTH dense one-hot incidence matrices [N_NODES, N_EDGES]
// (row-major). Exactly one nonzero per column -> plain stores are race-free.
//
// Round-2 structure (best measured: 1864 us): 4096 blocks x 256 threads,
// blocks [0,2048) scan Ri, [2048,4096) scan Ro, each block walks a
// contiguous 32768-float4 (512 KiB) chunk in 32 iterations of 4 independent
// 16B loads. SINGLE CHANGE vs round 2: plain loads instead of
// __builtin_nontemporal_load — isolating whether the `nt` L2-bypass flag is
// what caps the read path at ~4.3 TB/s (harness fill writes and the m13
// copy ubench both hit ~6.3 TB/s with plain accesses).
// ---------------------------------------------------------------------------

__device__ __forceinline__ void scan4i(vint4 v, int j, int* __restrict__ idx) {
    // Rare path: ~3% of wave-iterations have any hit -> execz-skippable.
    if ((v.x | v.y | v.z | v.w) != 0) {
        int n = j >> 13;             // row = j / E4
        int e = (j & (E4 - 1)) << 2; // col = (j % E4) * 4
        if (v.x != 0) idx[e + 0] = n;
        if (v.y != 0) idx[e + 1] = n;
        if (v.z != 0) idx[e + 2] = n;
        if (v.w != 0) idx[e + 3] = n;
    }
}

__global__ __launch_bounds__(256) void scan_both(const vint4* __restrict__ Ri4,
                                                 const vint4* __restrict__ Ro4,
                                                 int* __restrict__ idx_i,
                                                 int* __restrict__ idx_o) {
    int b = blockIdx.x;
    const vint4* __restrict__ mat = Ri4;
    int* __restrict__ idx = idx_i;
    if (b >= 2048) { mat = Ro4; idx = idx_o; b -= 2048; }

    int j = b * 32768 + (int)threadIdx.x;   // block-contiguous 512 KiB chunk
#pragma unroll 1
    for (int it = 0; it < 32; ++it, j += 1024) {
        vint4 v0 = mat[j];
        vint4 v1 = mat[j + 256];
        vint4 v2 = mat[j + 512];
        vint4 v3 = mat[j + 768];
        scan4i(v0, j,       idx);
        scan4i(v1, j + 256, idx);
        scan4i(v2, j + 512, idx);
        scan4i(v3, j + 768, idx);
    }
}

// ---------------------------------------------------------------------------
// Per-edge MLP: B = [X[idx_o[e]], X[idx_i[e]]] (bo first, matching the
// reference concatenate([bo, bi])), h = tanh(B @ W1 + b1),
// out = sigmoid(h @ W2 + b2). X (360 KB) + weights are L2-resident.
// ---------------------------------------------------------------------------

__global__ __launch_bounds__(256) void edge_mlp(const float* __restrict__ X,
                         const int*   __restrict__ idx_i,
                         const int*   __restrict__ idx_o,
                         const float* __restrict__ W1,  // [2*FEAT, HID]
                         const float* __restrict__ b1,  // [HID]
                         const float* __restrict__ W2,  // [HID]
                         const float* __restrict__ b2,  // [1]
                         float* __restrict__ out) {
    int e = blockIdx.x * blockDim.x + threadIdx.x;
    if (e >= N_EDGES) return;

    const float* xo = X + (long)idx_o[e] * FEAT;
    const float* xi = X + (long)idx_i[e] * FEAT;

    float h[HID];
#pragma unroll
    for (int j = 0; j < HID; ++j) h[j] = b1[j];

#pragma unroll
    for (int f = 0; f < FEAT; ++f) {
        float vo = xo[f];
        float vi = xi[f];
#pragma unroll
        for (int j = 0; j < HID; ++j) {
            h[j] += vo * W1[f * HID + j] + vi * W1[(FEAT + f) * HID + j];
        }
    }

    float acc = b2[0];
#pragma unroll
    for (int j = 0; j < HID; ++j) acc += tanhf(h[j]) * W2[j];

    out[e] = 1.0f / (1.0f + expf(-acc));
}

extern "C" void kernel_launch(void* const* d_in, const int* in_sizes, int n_in,
                              void* d_out, int out_size, void* d_ws, size_t ws_size,
                              hipStream_t stream) {
    const float* X  = (const float*)d_in[0];  // [8192, 11]
    const float* Ri = (const float*)d_in[1];  // [8192, 32768]
    const float* Ro = (const float*)d_in[2];  // [8192, 32768]
    const float* W1 = (const float*)d_in[3];  // [22, 8]
    const float* b1 = (const float*)d_in[4];  // [8]
    const float* W2 = (const float*)d_in[5];  // [8]
    const float* b2 = (const float*)d_in[6];  // [1]
    float* out = (float*)d_out;               // [32768]

    int* idx_i = (int*)d_ws;           // 32768 ints (every slot written by scan)
    int* idx_o = idx_i + N_EDGES;      // 32768 ints

    // One fused launch covering both matrices (2 GiB streaming read).
    scan_both<<<4096, 256, 0, stream>>>((const vint4*)Ri, (const vint4*)Ro,
                                        idx_i, idx_o);

    edge_mlp<<<(N_EDGES + 255) / 256, 256, 0, stream>>>(
        X, idx_i, idx_o, W1, b1, W2, b2, out);
}

// Round 6
// 1860.091 us; speedup vs baseline: 1.0582x; 1.0582x over previous
//
#include <hip/hip_runtime.h>
#include <math.h>

#define N_NODES 8192
#define N_EDGES 32768
#define HID 8
#define FEAT 11          // HID + 3
#define E4   (N_EDGES/4) // 8192 float4 per matrix row (2^13)

// Native clang vector type: __builtin_nontemporal_load requires a pointer to
// scalar/vector-of-scalar, which HIP's float4 (HIP_vector_type) is not.
typedef float vfloat4 __attribute__((ext_vector_type(4)));

// ---------------------------------------------------------------------------
// Fused scan of BOTH dense one-hot incidence matrices [N_NODES, N_EDGES]
// (row-major). Exactly one nonzero per column -> plain stores are race-free.
//
// BEST MEASURED CONFIG (round 2: 1863.8 us): 4096 blocks x 256 threads.
// Blocks [0,2048) scan Ri, [2048,4096) scan Ro. Each block owns a contiguous
// 32768-float4 (512 KiB) chunk and walks it in 32 iterations of 4
// independent nontemporal float4 loads. Probed and rejected alternatives:
//   8-deep pipelining        -> 1888 (neutral/worse)
//   grid-interleaved mapping -> 1954 (worse)
//   plain (non-nt) loads     -> 1968 (worse)
// Scan BW plateaus at ~4.35 TB/s across all variants: pure-read path
// ceiling (write path: 6.3 TB/s fills; copy: 3.15R+3.15W).
// ---------------------------------------------------------------------------

__device__ __forceinline__ void scan4(vfloat4 v, int j, int* __restrict__ idx) {
    // Rare path: P(any of 4 cols hits this row) ~ 4/8192 per lane,
    // ~3% per wave-iteration -> one execz-skippable branch for the wave.
    if (v.x != 0.0f || v.y != 0.0f || v.z != 0.0f || v.w != 0.0f) {
        int n = j >> 13;             // row = j / E4
        int e = (j & (E4 - 1)) << 2; // col = (j % E4) * 4
        if (v.x != 0.0f) idx[e + 0] = n;
        if (v.y != 0.0f) idx[e + 1] = n;
        if (v.z != 0.0f) idx[e + 2] = n;
        if (v.w != 0.0f) idx[e + 3] = n;
    }
}

__global__ __launch_bounds__(256) void scan_both(const vfloat4* __restrict__ Ri4,
                                                 const vfloat4* __restrict__ Ro4,
                                                 int* __restrict__ idx_i,
                                                 int* __restrict__ idx_o) {
    int b = blockIdx.x;
    const vfloat4* __restrict__ mat = Ri4;
    int* __restrict__ idx = idx_i;
    if (b >= 2048) { mat = Ro4; idx = idx_o; b -= 2048; }

    int j = b * 32768 + (int)threadIdx.x;   // block-contiguous 512 KiB chunk
#pragma unroll 1
    for (int it = 0; it < 32; ++it, j += 1024) {
        vfloat4 v0 = __builtin_nontemporal_load(mat + j);
        vfloat4 v1 = __builtin_nontemporal_load(mat + j + 256);
        vfloat4 v2 = __builtin_nontemporal_load(mat + j + 512);
        vfloat4 v3 = __builtin_nontemporal_load(mat + j + 768);
        scan4(v0, j,       idx);
        scan4(v1, j + 256, idx);
        scan4(v2, j + 512, idx);
        scan4(v3, j + 768, idx);
    }
}

// ---------------------------------------------------------------------------
// Per-edge MLP: B = [X[idx_o[e]], X[idx_i[e]]] (bo first, matching the
// reference concatenate([bo, bi])), h = tanh(B @ W1 + b1),
// out = sigmoid(h @ W2 + b2). X (360 KB) + weights are L2-resident.
// ---------------------------------------------------------------------------

__global__ __launch_bounds__(256) void edge_mlp(const float* __restrict__ X,
                         const int*   __restrict__ idx_i,
                         const int*   __restrict__ idx_o,
                         const float* __restrict__ W1,  // [2*FEAT, HID]
                         const float* __restrict__ b1,  // [HID]
                         const float* __restrict__ W2,  // [HID]
                         const float* __restrict__ b2,  // [1]
                         float* __restrict__ out) {
    int e = blockIdx.x * blockDim.x + threadIdx.x;
    if (e >= N_EDGES) return;

    const float* xo = X + (long)idx_o[e] * FEAT;
    const float* xi = X + (long)idx_i[e] * FEAT;

    float h[HID];
#pragma unroll
    for (int j = 0; j < HID; ++j) h[j] = b1[j];

#pragma unroll
    for (int f = 0; f < FEAT; ++f) {
        float vo = xo[f];
        float vi = xi[f];
#pragma unroll
        for (int j = 0; j < HID; ++j) {
            h[j] += vo * W1[f * HID + j] + vi * W1[(FEAT + f) * HID + j];
        }
    }

    float acc = b2[0];
#pragma unroll
    for (int j = 0; j < HID; ++j) acc += tanhf(h[j]) * W2[j];

    out[e] = 1.0f / (1.0f + expf(-acc));
}

extern "C" void kernel_launch(void* const* d_in, const int* in_sizes, int n_in,
                              void* d_out, int out_size, void* d_ws, size_t ws_size,
                              hipStream_t stream) {
    const float* X  = (const float*)d_in[0];  // [8192, 11]
    const float* Ri = (const float*)d_in[1];  // [8192, 32768]
    const float* Ro = (const float*)d_in[2];  // [8192, 32768]
    const float* W1 = (const float*)d_in[3];  // [22, 8]
    const float* b1 = (const float*)d_in[4];  // [8]
    const float* W2 = (const float*)d_in[5];  // [8]
    const float* b2 = (const float*)d_in[6];  // [1]
    float* out = (float*)d_out;               // [32768]

    int* idx_i = (int*)d_ws;           // 32768 ints (every slot written by scan)
    int* idx_o = idx_i + N_EDGES;      // 32768 ints

    // One fused launch covering both matrices (2 GiB streaming read).
    scan_both<<<4096, 256, 0, stream>>>((const vfloat4*)Ri, (const vfloat4*)Ro,
                                        idx_i, idx_o);

    edge_mlp<<<(N_EDGES + 255) / 256, 256, 0, stream>>>(
        X, idx_i, idx_o, W1, b1, W2, b2, out);
}